// Round 1
// baseline (3004.976 us; speedup 1.0000x reference)
//
#include <hip/hip_runtime.h>
#include <math.h>

#define B_ 2
#define S_ 2048
#define E_ 2048
#define H_ 16
#define DH_ 128
#define L_ 64

__device__ __forceinline__ float elu1(float x) {
    return x > 0.f ? x + 1.f : __expf(x);
}

__device__ __forceinline__ float gelu_tanh(float x) {
    // jax.nn.gelu approximate=True
    float z = 0.7978845608028654f * (x + 0.044715f * x * x * x);
    float az = fabsf(z);
    float e = __expf(-2.f * az);
    float t = (1.f - e) / (1.f + e);
    t = (z >= 0.f) ? t : -t;
    return 0.5f * x * (1.f + t);
}

// ---------------------------------------------------------------------------
// Generic C[M,N] = A[M,K] @ W[K,N] + bias   (f32, 64x64 tile, 4x4 microkernel)
// grid: (N/64, M/64), block 256
// ---------------------------------------------------------------------------
__global__ __launch_bounds__(256) void gemm_bias_f32(
    const float* __restrict__ A, const float* __restrict__ W,
    const float* __restrict__ bias, float* __restrict__ C,
    int M, int N, int K)
{
    __shared__ float As[16][68];  // As[k][m]
    __shared__ float Bs[16][68];  // Bs[k][n]
    const int tid = threadIdx.x;
    const int tx = tid & 15, ty = tid >> 4;
    const int row0 = blockIdx.y * 64;
    const int col0 = blockIdx.x * 64;

    const int am = tid >> 2;            // 0..63
    const int ak = (tid & 3) << 2;      // 0,4,8,12
    const int bk = tid >> 4;            // 0..15
    const int bn = (tid & 15) << 2;     // 0..60

    float acc[4][4] = {};
    for (int k0 = 0; k0 < K; k0 += 16) {
        float4 av = *reinterpret_cast<const float4*>(&A[(size_t)(row0 + am) * K + k0 + ak]);
        As[ak + 0][am] = av.x; As[ak + 1][am] = av.y;
        As[ak + 2][am] = av.z; As[ak + 3][am] = av.w;
        *reinterpret_cast<float4*>(&Bs[bk][bn]) =
            *reinterpret_cast<const float4*>(&W[(size_t)(k0 + bk) * N + col0 + bn]);
        __syncthreads();
        #pragma unroll
        for (int kk = 0; kk < 16; kk++) {
            float a[4], b[4];
            #pragma unroll
            for (int i = 0; i < 4; i++) a[i] = As[kk][ty * 4 + i];
            #pragma unroll
            for (int j = 0; j < 4; j++) b[j] = Bs[kk][tx * 4 + j];
            #pragma unroll
            for (int i = 0; i < 4; i++)
                #pragma unroll
                for (int j = 0; j < 4; j++)
                    acc[i][j] = fmaf(a[i], b[j], acc[i][j]);
        }
        __syncthreads();
    }
    #pragma unroll
    for (int i = 0; i < 4; i++) {
        const int r = row0 + ty * 4 + i;
        const int c = col0 + tx * 4;
        float4 o;
        o.x = acc[i][0] + bias[c + 0];
        o.y = acc[i][1] + bias[c + 1];
        o.z = acc[i][2] + bias[c + 2];
        o.w = acc[i][3] + bias[c + 3];
        *reinterpret_cast<float4*>(&C[(size_t)r * N + c]) = o;
    }
}

// ---------------------------------------------------------------------------
// Latent projection: OutLat[b,h,s,l] = elu1( sum_d Q[b,s,h*128+d] * Wl[d,l] + bl[l] )
// grid: (S/64, B*H), block 256
// ---------------------------------------------------------------------------
__global__ __launch_bounds__(256) void latent_proj(
    const float* __restrict__ Q, const float* __restrict__ Wl,
    const float* __restrict__ bl, float* __restrict__ OutLat)
{
    __shared__ float At[128][68];   // At[d][s]
    __shared__ float Ws[128][68];   // Ws[d][l]
    const int tid = threadIdx.x;
    const int s0 = blockIdx.x * 64;
    const int bh = blockIdx.y;
    const int b = bh >> 4, h = bh & 15;

    #pragma unroll
    for (int i = 0; i < 8; i++) {
        int idx = tid + i * 256;                 // 2048 float4 of W
        int d = idx >> 4, l4 = (idx & 15) << 2;
        *reinterpret_cast<float4*>(&Ws[d][l4]) =
            *reinterpret_cast<const float4*>(&Wl[d * 64 + l4]);
    }
    #pragma unroll
    for (int i = 0; i < 8; i++) {
        int idx = tid + i * 256;                 // 2048 float4 of A
        int s = idx >> 5, d4 = (idx & 31) << 2;
        float4 a4 = *reinterpret_cast<const float4*>(
            &Q[((size_t)(b * S_ + s0 + s)) * E_ + h * DH_ + d4]);
        At[d4 + 0][s] = a4.x; At[d4 + 1][s] = a4.y;
        At[d4 + 2][s] = a4.z; At[d4 + 3][s] = a4.w;
    }
    __syncthreads();

    const int tx = tid & 15, ty = tid >> 4;
    float acc[4][4] = {};
    #pragma unroll 8
    for (int d = 0; d < 128; d++) {
        float a[4], w[4];
        #pragma unroll
        for (int i = 0; i < 4; i++) a[i] = At[d][ty * 4 + i];
        #pragma unroll
        for (int j = 0; j < 4; j++) w[j] = Ws[d][tx * 4 + j];
        #pragma unroll
        for (int i = 0; i < 4; i++)
            #pragma unroll
            for (int j = 0; j < 4; j++)
                acc[i][j] = fmaf(a[i], w[j], acc[i][j]);
    }
    #pragma unroll
    for (int i = 0; i < 4; i++) {
        int s = s0 + ty * 4 + i;
        float4 o;
        int l = tx * 4;
        o.x = elu1(acc[i][0] + bl[l + 0]);
        o.y = elu1(acc[i][1] + bl[l + 1]);
        o.z = elu1(acc[i][2] + bl[l + 2]);
        o.w = elu1(acc[i][3] + bl[l + 3]);
        *reinterpret_cast<float4*>(&OutLat[((size_t)bh * S_ + s) * L_ + l]) = o;
    }
}

// ---------------------------------------------------------------------------
// Fused block attention: per (qblock of 128, b*h): loop 4 kv blocks of 512,
// online softmax over 64-key chunks within each kv block, normalize per block,
// sum over blocks. Writes AO[b,h,s,d].
// grid: (S/128, B*H), block 512
// ---------------------------------------------------------------------------
__global__ __launch_bounds__(512) void attn_kernel(
    const float* __restrict__ Qlat, const float* __restrict__ Klat,
    const float* __restrict__ V, float* __restrict__ AO)
{
    __shared__ float Qt[64][136];   // Qt[l][q]
    __shared__ float Kt[64][68];    // Kt[l][f]
    __shared__ float Pt[64][136];   // Pt[f][q]  (scores, then probs, transposed)
    __shared__ float Vs[64][136];   // Vs[f][d]
    __shared__ float mrow[128], lrow[128], arow[128];

    const int tid = threadIdx.x;
    const int qi = blockIdx.x, bh = blockIdx.y;
    const int b = bh >> 4, h = bh & 15;
    const int tx = tid & 15;        // d/f column group
    const int ty = tid >> 4;        // 0..31, q rows ty*4..ty*4+3

    #pragma unroll
    for (int i = 0; i < 4; i++) {
        int idx = tid + i * 512;                 // 2048 float4
        int q = idx >> 4, l4 = (idx & 15) << 2;
        float4 v4 = *reinterpret_cast<const float4*>(
            &Qlat[((size_t)bh * S_ + qi * 128 + q) * L_ + l4]);
        Qt[l4 + 0][q] = v4.x; Qt[l4 + 1][q] = v4.y;
        Qt[l4 + 2][q] = v4.z; Qt[l4 + 3][q] = v4.w;
    }

    float o_tot[4][8] = {};
    for (int kb = 0; kb < 4; kb++) {
        float o_par[4][8] = {};
        __syncthreads();   // previous fold's lrow reads done
        if (tid < 128) { mrow[tid] = -1e30f; lrow[tid] = 0.f; }
        for (int fc = 0; fc < 8; fc++) {
            const int f0 = kb * 512 + fc * 64;
            __syncthreads();   // previous PV reads of Pt/Vs done; init visible
            #pragma unroll
            for (int i = 0; i < 2; i++) {
                int idx = tid + i * 512;         // 1024 float4 of K chunk
                int f = idx >> 4, l4 = (idx & 15) << 2;
                float4 v4 = *reinterpret_cast<const float4*>(
                    &Klat[((size_t)bh * S_ + f0 + f) * L_ + l4]);
                Kt[l4 + 0][f] = v4.x; Kt[l4 + 1][f] = v4.y;
                Kt[l4 + 2][f] = v4.z; Kt[l4 + 3][f] = v4.w;
            }
            #pragma unroll
            for (int i = 0; i < 4; i++) {
                int idx = tid + i * 512;         // 2048 float4 of V chunk
                int f = idx >> 5, d4 = (idx & 31) << 2;
                *reinterpret_cast<float4*>(&Vs[f][d4]) =
                    *reinterpret_cast<const float4*>(
                        &V[((size_t)(b * S_ + f0 + f)) * E_ + h * DH_ + d4]);
            }
            __syncthreads();
            // QK^T chunk: rows q=ty*4.., cols f=tx*4..
            float sacc[4][4] = {};
            #pragma unroll 8
            for (int l = 0; l < 64; l++) {
                float a[4], kx[4];
                #pragma unroll
                for (int i = 0; i < 4; i++) a[i] = Qt[l][ty * 4 + i];
                #pragma unroll
                for (int j = 0; j < 4; j++) kx[j] = Kt[l][tx * 4 + j];
                #pragma unroll
                for (int i = 0; i < 4; i++)
                    #pragma unroll
                    for (int j = 0; j < 4; j++)
                        sacc[i][j] = fmaf(a[i], kx[j], sacc[i][j]);
            }
            #pragma unroll
            for (int i = 0; i < 4; i++)
                #pragma unroll
                for (int j = 0; j < 4; j++)
                    Pt[tx * 4 + j][ty * 4 + i] = sacc[i][j] * 0.125f;
            __syncthreads();
            // online softmax update per q row (axis = this 64-key chunk)
            if (tid < 128) {
                const int q = tid;
                float mold = mrow[q];
                float mx = mold;
                #pragma unroll 8
                for (int f = 0; f < 64; f++) mx = fmaxf(mx, Pt[f][q]);
                float alpha = __expf(mold - mx);
                float sum = 0.f;
                #pragma unroll 8
                for (int f = 0; f < 64; f++) {
                    float p = __expf(Pt[f][q] - mx);
                    Pt[f][q] = p;
                    sum += p;
                }
                lrow[q] = lrow[q] * alpha + sum;
                mrow[q] = mx;
                arow[q] = alpha;
            }
            __syncthreads();
            float al[4];
            #pragma unroll
            for (int i = 0; i < 4; i++) al[i] = arow[ty * 4 + i];
            #pragma unroll
            for (int i = 0; i < 4; i++)
                #pragma unroll
                for (int j = 0; j < 8; j++)
                    o_par[i][j] *= al[i];
            // PV chunk: o_par[q][d] += P[q][f] * V[f][d]; d cols tx*4 and 64+tx*4
            #pragma unroll 4
            for (int f = 0; f < 64; f++) {
                float a[4], vv[8];
                #pragma unroll
                for (int i = 0; i < 4; i++) a[i] = Pt[f][ty * 4 + i];
                #pragma unroll
                for (int j = 0; j < 4; j++) {
                    vv[j]     = Vs[f][tx * 4 + j];
                    vv[4 + j] = Vs[f][64 + tx * 4 + j];
                }
                #pragma unroll
                for (int i = 0; i < 4; i++)
                    #pragma unroll
                    for (int j = 0; j < 8; j++)
                        o_par[i][j] = fmaf(a[i], vv[j], o_par[i][j]);
            }
        }
        // fold this kv block: o_tot += o_par / l   (lrow final; written before last barrier)
        float linv[4];
        #pragma unroll
        for (int i = 0; i < 4; i++) linv[i] = 1.f / lrow[ty * 4 + i];
        #pragma unroll
        for (int i = 0; i < 4; i++)
            #pragma unroll
            for (int j = 0; j < 8; j++)
                o_tot[i][j] += o_par[i][j] * linv[i];
    }
    #pragma unroll
    for (int i = 0; i < 4; i++) {
        int q = qi * 128 + ty * 4 + i;
        float4 o0, o1;
        o0.x = o_tot[i][0]; o0.y = o_tot[i][1]; o0.z = o_tot[i][2]; o0.w = o_tot[i][3];
        o1.x = o_tot[i][4]; o1.y = o_tot[i][5]; o1.z = o_tot[i][6]; o1.w = o_tot[i][7];
        float* base = &AO[((size_t)bh * S_ + q) * DH_];
        *reinterpret_cast<float4*>(&base[tx * 4]) = o0;
        *reinterpret_cast<float4*>(&base[64 + tx * 4]) = o1;
    }
}

// ---------------------------------------------------------------------------
// Mixer: Mixed[b,s,h*128+n] = gelu( sum_d AO[b,h,s,d]*Wm[d,n] + bm[n] )
// grid: (S/64, B*H), block 256
// ---------------------------------------------------------------------------
__global__ __launch_bounds__(256) void mixer_proj(
    const float* __restrict__ AO, const float* __restrict__ Wm,
    const float* __restrict__ bm, float* __restrict__ Mixed)
{
    __shared__ float At[128][68];    // At[d][s]
    __shared__ float Ws[128][132];   // Ws[d][n]
    const int tid = threadIdx.x;
    const int s0 = blockIdx.x * 64;
    const int bh = blockIdx.y;
    const int b = bh >> 4, h = bh & 15;

    #pragma unroll
    for (int i = 0; i < 16; i++) {
        int idx = tid + i * 256;                 // 4096 float4 of Wm
        int d = idx >> 5, n4 = (idx & 31) << 2;
        *reinterpret_cast<float4*>(&Ws[d][n4]) =
            *reinterpret_cast<const float4*>(&Wm[d * 128 + n4]);
    }
    #pragma unroll
    for (int i = 0; i < 8; i++) {
        int idx = tid + i * 256;                 // 2048 float4 of AO
        int s = idx >> 5, d4 = (idx & 31) << 2;
        float4 a4 = *reinterpret_cast<const float4*>(
            &AO[((size_t)bh * S_ + s0 + s) * DH_ + d4]);
        At[d4 + 0][s] = a4.x; At[d4 + 1][s] = a4.y;
        At[d4 + 2][s] = a4.z; At[d4 + 3][s] = a4.w;
    }
    __syncthreads();

    const int tx = tid & 15, ty = tid >> 4;
    float acc[4][8] = {};
    #pragma unroll 4
    for (int d = 0; d < 128; d++) {
        float a[4], w[8];
        #pragma unroll
        for (int i = 0; i < 4; i++) a[i] = At[d][ty * 4 + i];
        #pragma unroll
        for (int j = 0; j < 4; j++) {
            w[j]     = Ws[d][tx * 4 + j];
            w[4 + j] = Ws[d][64 + tx * 4 + j];
        }
        #pragma unroll
        for (int i = 0; i < 4; i++)
            #pragma unroll
            for (int j = 0; j < 8; j++)
                acc[i][j] = fmaf(a[i], w[j], acc[i][j]);
    }
    #pragma unroll
    for (int i = 0; i < 4; i++) {
        int s = s0 + ty * 4 + i;
        float* base = &Mixed[((size_t)(b * S_ + s)) * E_ + h * DH_];
        float4 o0, o1;
        o0.x = gelu_tanh(acc[i][0] + bm[tx * 4 + 0]);
        o0.y = gelu_tanh(acc[i][1] + bm[tx * 4 + 1]);
        o0.z = gelu_tanh(acc[i][2] + bm[tx * 4 + 2]);
        o0.w = gelu_tanh(acc[i][3] + bm[tx * 4 + 3]);
        o1.x = gelu_tanh(acc[i][4] + bm[64 + tx * 4 + 0]);
        o1.y = gelu_tanh(acc[i][5] + bm[64 + tx * 4 + 1]);
        o1.z = gelu_tanh(acc[i][6] + bm[64 + tx * 4 + 2]);
        o1.w = gelu_tanh(acc[i][7] + bm[64 + tx * 4 + 3]);
        *reinterpret_cast<float4*>(&base[tx * 4]) = o0;
        *reinterpret_cast<float4*>(&base[64 + tx * 4]) = o1;
    }
}

extern "C" void kernel_launch(void* const* d_in, const int* in_sizes, int n_in,
                              void* d_out, int out_size, void* d_ws, size_t ws_size,
                              hipStream_t stream)
{
    const float* x   = (const float*)d_in[0];
    const float* Wq  = (const float*)d_in[1];
    const float* bq  = (const float*)d_in[2];
    const float* Wk  = (const float*)d_in[3];
    const float* bk  = (const float*)d_in[4];
    const float* Wv  = (const float*)d_in[5];
    const float* bv  = (const float*)d_in[6];
    const float* Wo  = (const float*)d_in[7];
    const float* bo  = (const float*)d_in[8];
    const float* Wql = (const float*)d_in[9];
    const float* bql = (const float*)d_in[10];
    const float* Wkl = (const float*)d_in[11];
    const float* bkl = (const float*)d_in[12];
    const float* Wm  = (const float*)d_in[13];
    const float* bm  = (const float*)d_in[14];
    float* out = (float*)d_out;

    float* ws = (float*)d_ws;
    const size_t QKV = (size_t)B_ * S_ * E_;       // 8388608 floats
    const size_t LAT = (size_t)B_ * H_ * S_ * L_;  // 4194304 floats
    float* bufA = ws;               // q -> k -> attn_out
    float* bufB = ws + QKV;         // v -> mixed
    float* qlat = ws + 2 * QKV;
    float* klat = qlat + LAT;

    dim3 gemm_g(E_ / 64, (B_ * S_) / 64);   // (32, 64)
    dim3 lat_g(S_ / 64, B_ * H_);           // (32, 32)
    dim3 attn_g(S_ / 128, B_ * H_);         // (16, 32)

    // q -> qlat
    gemm_bias_f32<<<gemm_g, 256, 0, stream>>>(x, Wq, bq, bufA, B_ * S_, E_, E_);
    latent_proj<<<lat_g, 256, 0, stream>>>(bufA, Wql, bql, qlat);
    // k -> klat (reuse bufA)
    gemm_bias_f32<<<gemm_g, 256, 0, stream>>>(x, Wk, bk, bufA, B_ * S_, E_, E_);
    latent_proj<<<lat_g, 256, 0, stream>>>(bufA, Wkl, bkl, klat);
    // v
    gemm_bias_f32<<<gemm_g, 256, 0, stream>>>(x, Wv, bv, bufB, B_ * S_, E_, E_);
    // attention -> bufA (AO [B,H,S,DH])
    attn_kernel<<<attn_g, 512, 0, stream>>>(qlat, klat, bufB, bufA);
    // mixer -> bufB as Mixed [B,S,E]
    mixer_proj<<<lat_g, 256, 0, stream>>>(bufA, Wm, bm, bufB);
    // final projection
    gemm_bias_f32<<<gemm_g, 256, 0, stream>>>(bufB, Wo, bo, out, B_ * S_, E_, E_);
}

// Round 3
// 464.086 us; speedup vs baseline: 6.4750x; 6.4750x over previous
//
#include <hip/hip_runtime.h>
#include <stdint.h>
#include <math.h>

#define B_ 2
#define S_ 2048
#define E_ 2048
#define H_ 16
#define DH_ 128
#define L_ 64

typedef unsigned short u16;
typedef __attribute__((ext_vector_type(4))) float f32x4;
typedef __attribute__((ext_vector_type(8))) short short8;

__device__ __forceinline__ u16 f2bf(float f) {
    union { float f; uint32_t u; } c; c.f = f;
    uint32_t u = c.u + 0x7fff + ((c.u >> 16) & 1);
    return (u16)(u >> 16);
}
__device__ __forceinline__ float bf2f(u16 h) {
    union { uint32_t u; float f; } c; c.u = ((uint32_t)h) << 16;
    return c.f;
}
__device__ __forceinline__ float elu1(float x) {
    return x > 0.f ? x + 1.f : __expf(x);
}
__device__ __forceinline__ float gelu_tanh(float x) {
    float z = 0.7978845608028654f * (x + 0.044715f * x * x * x);
    float az = fabsf(z);
    float e = __expf(-2.f * az);
    float t = (1.f - e) / (1.f + e);
    t = (z >= 0.f) ? t : -t;
    return 0.5f * x * (1.f + t);
}
// async global->LDS, 16B per lane, LDS dest lane-linear (wave-uniform base + lane*16)
__device__ __forceinline__ void async16(u16* lds_dst, const u16* g_src) {
    __builtin_amdgcn_global_load_lds(
        (const __attribute__((address_space(1))) uint32_t*)g_src,
        (__attribute__((address_space(3))) uint32_t*)lds_dst, 16, 0, 0);
}
// element offset within a row for swizzled 8-u16 chunk reads:
// storage has chunk c of row at (c ^ (row&7))*8
__device__ __forceinline__ int swz_off(int row, int chunk) {
    return ((chunk ^ (row & 7)) << 3);
}

// ---------------------------------------------------------------------------
// f32 -> bf16 elementwise, 8/thread
// ---------------------------------------------------------------------------
__global__ __launch_bounds__(256) void cvt_bf16(const float* __restrict__ in,
                                                u16* __restrict__ out, int n8) {
    for (int i = blockIdx.x * 256 + threadIdx.x; i < n8; i += gridDim.x * 256) {
        float4 a = reinterpret_cast<const float4*>(in)[2 * i];
        float4 b = reinterpret_cast<const float4*>(in)[2 * i + 1];
        u16 u[8] __attribute__((aligned(16)));
        u[0] = f2bf(a.x); u[1] = f2bf(a.y); u[2] = f2bf(a.z); u[3] = f2bf(a.w);
        u[4] = f2bf(b.x); u[5] = f2bf(b.y); u[6] = f2bf(b.z); u[7] = f2bf(b.w);
        reinterpret_cast<int4*>(out)[i] = *(const int4*)u;
    }
}

// ---------------------------------------------------------------------------
// W[K][N] f32 -> Wt[N][K] bf16  (64x64 tiles)
// ---------------------------------------------------------------------------
__global__ __launch_bounds__(256) void wtrans(const float* __restrict__ W,
                                              u16* __restrict__ Wt, int K, int N) {
    __shared__ u16 t[64][68];
    const int tid = threadIdx.x;
    const int n0 = blockIdx.x * 64, k0 = blockIdx.y * 64;
    const int c4 = (tid & 15) * 4, r = tid >> 4;
    #pragma unroll
    for (int i = 0; i < 4; i++) {
        int row = r + 16 * i;
        float4 v = *reinterpret_cast<const float4*>(&W[(size_t)(k0 + row) * N + n0 + c4]);
        t[c4 + 0][row] = f2bf(v.x); t[c4 + 1][row] = f2bf(v.y);
        t[c4 + 2][row] = f2bf(v.z); t[c4 + 3][row] = f2bf(v.w);
    }
    __syncthreads();
    #pragma unroll
    for (int i = 0; i < 4; i++) {
        int nr = r + 16 * i;
        ushort4 o = *reinterpret_cast<const ushort4*>(&t[nr][c4]);
        *reinterpret_cast<ushort4*>(&Wt[(size_t)(n0 + nr) * K + k0 + c4]) = o;
    }
}

// ---------------------------------------------------------------------------
// v[b][s][h*128+d] bf16 -> Vt[bh][d][s] bf16 (64x64 tiles)
// grid: ((S/64)*2, B*H)
// ---------------------------------------------------------------------------
__global__ __launch_bounds__(256) void vtrans(const u16* __restrict__ vb,
                                              u16* __restrict__ Vt) {
    __shared__ u16 t[64][66];
    const int bh = blockIdx.y, b = bh >> 4, h = bh & 15;
    const int s0 = (blockIdx.x >> 1) * 64, d0 = (blockIdx.x & 1) * 64;
    const int tid = threadIdx.x;
    const int rr = tid >> 3, c8 = (tid & 7) * 8;
    #pragma unroll
    for (int i = 0; i < 2; i++) {
        int sr = rr + 32 * i;
        int4 v = *reinterpret_cast<const int4*>(
            &vb[((size_t)(b * S_) + s0 + sr) * E_ + h * DH_ + d0 + c8]);
        const u16* pv = (const u16*)&v;
        #pragma unroll
        for (int j = 0; j < 8; j++) t[sr][c8 + j] = pv[j];
    }
    __syncthreads();
    #pragma unroll
    for (int i = 0; i < 2; i++) {
        int dr = rr + 32 * i;
        u16 u[8] __attribute__((aligned(16)));
        #pragma unroll
        for (int j = 0; j < 8; j++) u[j] = t[c8 + j][dr];
        *reinterpret_cast<int4*>(&Vt[((size_t)(bh * 128) + d0 + dr) * S_ + s0 + c8]) =
            *(const int4*)u;
    }
}

// ---------------------------------------------------------------------------
// C[M,N] = A[M,K]bf16 @ Wt[N,K]bf16^T + bias. 128x128 tile, BK=64, 4 waves.
// DUAL: C = (A + A2) @ Wt^T (split-bf16 A for precision).
// grid (N/128, M/128), block 256.
// ---------------------------------------------------------------------------
template <typename OutT, bool DUAL>
__global__ __launch_bounds__(256) void gemm_bf16(
    const u16* __restrict__ A, const u16* __restrict__ A2,
    const u16* __restrict__ Wt, const float* __restrict__ bias,
    OutT* __restrict__ C, int M, int N, int K)
{
    __shared__ u16 lds[DUAL ? 24576 : 16384];
    const int tid = threadIdx.x, l = tid & 63, w = tid >> 6;
    const int wr = w >> 1, wc = w & 1;
    const int row0 = blockIdx.y * 128, col0 = blockIdx.x * 128;

    f32x4 zero = {0.f, 0.f, 0.f, 0.f};
    f32x4 acc[4][4];
    #pragma unroll
    for (int i = 0; i < 4; i++)
        #pragma unroll
        for (int j = 0; j < 4; j++) acc[i][j] = zero;

    for (int k0 = 0; k0 < K; k0 += 64) {
        #pragma unroll
        for (int i = 0; i < 4; i++) {
            int lin = i * 256 + tid, row = lin >> 3, c = lin & 7;
            int sc = swz_off(row, c);
            async16(&lds[lin * 8], &A[(size_t)(row0 + row) * K + k0 + sc]);
            async16(&lds[8192 + lin * 8], &Wt[(size_t)(col0 + row) * K + k0 + sc]);
            if (DUAL) async16(&lds[16384 + lin * 8], &A2[(size_t)(row0 + row) * K + k0 + sc]);
        }
        __syncthreads();
        #pragma unroll
        for (int ks = 0; ks < 2; ks++) {
            short8 af[4], bf[4], af2[4];
            #pragma unroll
            for (int mi = 0; mi < 4; mi++) {
                int row = 64 * wr + 16 * mi + (l & 15);
                int idx = row * 64 + swz_off(row, ks * 4 + (l >> 4));
                af[mi] = *reinterpret_cast<const short8*>(&lds[idx]);
                if (DUAL) af2[mi] = *reinterpret_cast<const short8*>(&lds[16384 + idx]);
            }
            #pragma unroll
            for (int ni = 0; ni < 4; ni++) {
                int row = 64 * wc + 16 * ni + (l & 15);
                int idx = 8192 + row * 64 + swz_off(row, ks * 4 + (l >> 4));
                bf[ni] = *reinterpret_cast<const short8*>(&lds[idx]);
            }
            #pragma unroll
            for (int mi = 0; mi < 4; mi++)
                #pragma unroll
                for (int ni = 0; ni < 4; ni++) {
                    acc[mi][ni] = __builtin_amdgcn_mfma_f32_16x16x32_bf16(
                        af[mi], bf[ni], acc[mi][ni], 0, 0, 0);
                    if (DUAL)
                        acc[mi][ni] = __builtin_amdgcn_mfma_f32_16x16x32_bf16(
                            af2[mi], bf[ni], acc[mi][ni], 0, 0, 0);
                }
        }
        __syncthreads();
    }
    #pragma unroll
    for (int mi = 0; mi < 4; mi++)
        #pragma unroll
        for (int ni = 0; ni < 4; ni++) {
            int col = col0 + 64 * wc + 16 * ni + (l & 15);
            float bv = bias[col];
            #pragma unroll
            for (int j = 0; j < 4; j++) {
                int row = row0 + 64 * wr + 16 * mi + (l >> 4) * 4 + j;
                float v = acc[mi][ni][j] + bv;
                if (sizeof(OutT) == 2)
                    C[(size_t)row * N + col] = (OutT)f2bf(v);
                else
                    C[(size_t)row * N + col] = (OutT)v;
            }
        }
}

// ---------------------------------------------------------------------------
// Per-head small GEMM, K=128 one-shot. MODE 0: latent (NT=64, elu+1, bf16 out
// [bh][s][64]); MODE 1: mixer (NT=128, gelu, dual bf16 hi/lo out [b][s][E]).
// grid (S/128, B*H), block 256.
// ---------------------------------------------------------------------------
template <int MODE>
__global__ __launch_bounds__(256) void headgemm(
    const u16* __restrict__ A, const u16* __restrict__ Wt,
    const float* __restrict__ bias, u16* __restrict__ out, u16* __restrict__ out2)
{
    constexpr int NT = (MODE == 0) ? 64 : 128;
    __shared__ u16 lds[16384 + NT * 128];
    const int tid = threadIdx.x, l = tid & 63, w = tid >> 6;
    const int s0 = blockIdx.x * 128, bh = blockIdx.y, b = bh >> 4, h = bh & 15;

    #pragma unroll
    for (int i = 0; i < 8; i++) {
        int lin = i * 256 + tid, row = lin >> 4, c = lin & 15;
        int sc = swz_off(row, c);
        const u16* src = (MODE == 0)
            ? &A[((size_t)(b * S_ + s0 + row)) * E_ + h * DH_ + sc]
            : &A[((size_t)(bh * S_ + s0 + row)) * DH_ + sc];
        async16(&lds[lin * 8], src);
    }
    #pragma unroll
    for (int i = 0; i < NT * 16 / 256; i++) {
        int lin = i * 256 + tid, n = lin >> 4, c = lin & 15;
        int sc = swz_off(n, c);
        async16(&lds[16384 + lin * 8], &Wt[(size_t)n * 128 + sc]);
    }
    __syncthreads();

    f32x4 zero = {0.f, 0.f, 0.f, 0.f};
    f32x4 acc[2][NT / 16];
    #pragma unroll
    for (int mi = 0; mi < 2; mi++)
        #pragma unroll
        for (int ni = 0; ni < NT / 16; ni++) acc[mi][ni] = zero;

    #pragma unroll
    for (int ks = 0; ks < 4; ks++) {
        short8 af[2];
        #pragma unroll
        for (int mi = 0; mi < 2; mi++) {
            int row = 32 * w + 16 * mi + (l & 15);
            int idx = row * 128 + swz_off(row, ks * 4 + (l >> 4));
            af[mi] = *reinterpret_cast<const short8*>(&lds[idx]);
        }
        #pragma unroll
        for (int ni = 0; ni < NT / 16; ni++) {
            int n = 16 * ni + (l & 15);
            int idx = 16384 + n * 128 + swz_off(n, ks * 4 + (l >> 4));
            short8 bf = *reinterpret_cast<const short8*>(&lds[idx]);
            #pragma unroll
            for (int mi = 0; mi < 2; mi++)
                acc[mi][ni] = __builtin_amdgcn_mfma_f32_16x16x32_bf16(
                    af[mi], bf, acc[mi][ni], 0, 0, 0);
        }
    }

    #pragma unroll
    for (int mi = 0; mi < 2; mi++)
        #pragma unroll
        for (int ni = 0; ni < NT / 16; ni++) {
            int col = 16 * ni + (l & 15);
            float bv = bias[col];
            #pragma unroll
            for (int j = 0; j < 4; j++) {
                int q = s0 + 32 * w + 16 * mi + (l >> 4) * 4 + j;
                float v = acc[mi][ni][j] + bv;
                if (MODE == 0) {
                    v = elu1(v);
                    out[((size_t)bh * S_ + q) * 64 + col] = f2bf(v);
                } else {
                    v = gelu_tanh(v);
                    u16 hi = f2bf(v);
                    float rem = v - bf2f(hi);
                    size_t o = ((size_t)(b * S_ + q)) * E_ + h * DH_ + col;
                    out[o] = hi;
                    out2[o] = f2bf(rem);
                }
            }
        }
}

// ---------------------------------------------------------------------------
// Fused block attention, MFMA. Per (128-q tile, bh). 4 kv blocks of 512;
// each processed in 4 chunks of 128 keys with in-register online softmax.
// LDS pool: [0,16384) Q then P; [16384,24576) K chunk; [24576,40960) Vt chunk.
// grid (S/128, B*H), block 256 (4 waves, each 32 q-rows).
// ---------------------------------------------------------------------------
__global__ __launch_bounds__(256) void attn_mfma(
    const u16* __restrict__ qlat, const u16* __restrict__ klat,
    const u16* __restrict__ Vt, u16* __restrict__ AO)
{
    __shared__ u16 pool[40960];
    const int tid = threadIdx.x, l = tid & 63, w = tid >> 6;
    const int qi = blockIdx.x, bh = blockIdx.y;
    const size_t latBase = (size_t)bh * S_ * L_;
    const int q0 = qi * 128;

    // stage Q [128][64] (swizzled source)
    #pragma unroll
    for (int i = 0; i < 4; i++) {
        int lin = i * 256 + tid, row = lin >> 3, c = lin & 7;
        async16(&pool[lin * 8], &qlat[latBase + (size_t)(q0 + row) * 64 + swz_off(row, c)]);
    }
    __syncthreads();
    short8 qf[2][2];
    #pragma unroll
    for (int mi = 0; mi < 2; mi++)
        #pragma unroll
        for (int ks = 0; ks < 2; ks++) {
            int row = 32 * w + 16 * mi + (l & 15);
            int idx = row * 64 + swz_off(row, ks * 4 + (l >> 4));
            qf[mi][ks] = *reinterpret_cast<const short8*>(&pool[idx]);
        }

    f32x4 zero = {0.f, 0.f, 0.f, 0.f};
    f32x4 Ot[2][8];
    #pragma unroll
    for (int mi = 0; mi < 2; mi++)
        #pragma unroll
        for (int nd = 0; nd < 8; nd++) Ot[mi][nd] = zero;

    for (int kb = 0; kb < 4; kb++) {
        f32x4 Op[2][8];
        float m_reg[2][4], l_reg[2][4];
        #pragma unroll
        for (int mi = 0; mi < 2; mi++) {
            #pragma unroll
            for (int nd = 0; nd < 8; nd++) Op[mi][nd] = zero;
            #pragma unroll
            for (int j = 0; j < 4; j++) { m_reg[mi][j] = -1e30f; l_reg[mi][j] = 0.f; }
        }
        for (int fc = 0; fc < 4; fc++) {
            const int f0 = kb * 512 + fc * 128;
            __syncthreads();   // prior chunk's K/V reads complete before restaging
            #pragma unroll
            for (int i = 0; i < 4; i++) {
                int lin = i * 256 + tid, row = lin >> 3, c = lin & 7;
                async16(&pool[16384 + lin * 8],
                        &klat[latBase + (size_t)(f0 + row) * 64 + swz_off(row, c)]);
            }
            #pragma unroll
            for (int i = 0; i < 8; i++) {
                int lin = i * 256 + tid, d = lin >> 4, c = lin & 15;
                async16(&pool[24576 + lin * 8],
                        &Vt[(size_t)(bh * 128 + d) * S_ + f0 + swz_off(d, c)]);
            }
            __syncthreads();   // drains vmcnt: K,V ready

            // scores: accS[mi][ni] = Q(32 rows) x K(128 keys), K-dim L=64
            f32x4 accS[2][8];
            #pragma unroll
            for (int mi = 0; mi < 2; mi++)
                #pragma unroll
                for (int ni = 0; ni < 8; ni++) accS[mi][ni] = zero;
            #pragma unroll
            for (int ks = 0; ks < 2; ks++)
                #pragma unroll
                for (int ni = 0; ni < 8; ni++) {
                    int row = 16 * ni + (l & 15);
                    int idx = 16384 + row * 64 + swz_off(row, ks * 4 + (l >> 4));
                    short8 kf = *reinterpret_cast<const short8*>(&pool[idx]);
                    #pragma unroll
                    for (int mi = 0; mi < 2; mi++)
                        accS[mi][ni] = __builtin_amdgcn_mfma_f32_16x16x32_bf16(
                            qf[mi][ks], kf, accS[mi][ni], 0, 0, 0);
                }

            // in-register online softmax (rows = (l>>4)*4+j within 16-row tile)
            #pragma unroll
            for (int mi = 0; mi < 2; mi++)
                #pragma unroll
                for (int j = 0; j < 4; j++) {
                    float mx = -1e30f;
                    #pragma unroll
                    for (int ni = 0; ni < 8; ni++) mx = fmaxf(mx, accS[mi][ni][j]);
                    mx *= 0.125f;
                    #pragma unroll
                    for (int d = 1; d < 16; d <<= 1) mx = fmaxf(mx, __shfl_xor(mx, d));
                    float mo = m_reg[mi][j];
                    float mn = fmaxf(mo, mx);
                    float alpha = __expf(mo - mn);
                    int qloc = 32 * w + 16 * mi + (l >> 4) * 4 + j;
                    float sum = 0.f;
                    #pragma unroll
                    for (int ni = 0; ni < 8; ni++) {
                        float p = __expf(accS[mi][ni][j] * 0.125f - mn);
                        sum += p;
                        int floc = 16 * ni + (l & 15);
                        pool[(qloc * 128 + floc) ^ ((qloc & 7) << 3)] = f2bf(p);
                    }
                    #pragma unroll
                    for (int d = 1; d < 16; d <<= 1) sum += __shfl_xor(sum, d);
                    l_reg[mi][j] = l_reg[mi][j] * alpha + sum;
                    m_reg[mi][j] = mn;
                    #pragma unroll
                    for (int nd = 0; nd < 8; nd++) Op[mi][nd][j] *= alpha;
                }

            // PV: Op[32 q][128 d] += P[32 q][128 f] x Vt[128 d][128 f]^T
            // (P is wave-private: written and read by the same wave.)
            #pragma unroll
            for (int ks = 0; ks < 4; ks++) {
                short8 pa[2];
                #pragma unroll
                for (int mi = 0; mi < 2; mi++) {
                    int qloc = 32 * w + 16 * mi + (l & 15);
                    int idx = qloc * 128 + swz_off(qloc, ks * 4 + (l >> 4));
                    pa[mi] = *reinterpret_cast<const short8*>(&pool[idx]);
                }
                #pragma unroll
                for (int nd = 0; nd < 8; nd++) {
                    int d = 16 * nd + (l & 15);
                    int idx = 24576 + d * 128 + swz_off(d, ks * 4 + (l >> 4));
                    short8 vb = *reinterpret_cast<const short8*>(&pool[idx]);
                    #pragma unroll
                    for (int mi = 0; mi < 2; mi++)
                        Op[mi][nd] = __builtin_amdgcn_mfma_f32_16x16x32_bf16(
                            pa[mi], vb, Op[mi][nd], 0, 0, 0);
                }
            }
        }
        // fold kv block: Ot += Op / l
        #pragma unroll
        for (int mi = 0; mi < 2; mi++)
            #pragma unroll
            for (int j = 0; j < 4; j++) {
                float linv = 1.f / l_reg[mi][j];
                #pragma unroll
                for (int nd = 0; nd < 8; nd++) Ot[mi][nd][j] += Op[mi][nd][j] * linv;
            }
    }

    #pragma unroll
    for (int mi = 0; mi < 2; mi++)
        #pragma unroll
        for (int nd = 0; nd < 8; nd++) {
            int d = 16 * nd + (l & 15);
            #pragma unroll
            for (int j = 0; j < 4; j++) {
                int q = q0 + 32 * w + 16 * mi + (l >> 4) * 4 + j;
                AO[((size_t)bh * S_ + q) * 128 + d] = f2bf(Ot[mi][nd][j]);
            }
        }
}

// ---------------------------------------------------------------------------
extern "C" void kernel_launch(void* const* d_in, const int* in_sizes, int n_in,
                              void* d_out, int out_size, void* d_ws, size_t ws_size,
                              hipStream_t stream)
{
    const float* x   = (const float*)d_in[0];
    const float* Wq  = (const float*)d_in[1];
    const float* bq  = (const float*)d_in[2];
    const float* Wk  = (const float*)d_in[3];
    const float* bk  = (const float*)d_in[4];
    const float* Wv  = (const float*)d_in[5];
    const float* bv  = (const float*)d_in[6];
    const float* Wo  = (const float*)d_in[7];
    const float* bo  = (const float*)d_in[8];
    const float* Wql = (const float*)d_in[9];
    const float* bql = (const float*)d_in[10];
    const float* Wkl = (const float*)d_in[11];
    const float* bkl = (const float*)d_in[12];
    const float* Wm  = (const float*)d_in[13];
    const float* bm  = (const float*)d_in[14];
    float* out = (float*)d_out;

    u16* ws0  = (u16*)d_ws;
    u16* xb   = ws0;                      // 8,388,608
    u16* Wqt  = ws0 + 8388608;            // 4,194,304
    u16* Wkt  = Wqt + 4194304;
    u16* Wvt  = Wkt + 4194304;
    u16* Wot  = Wvt + 4194304;
    u16* Wmt  = Wot + 4194304;            // 16,384
    u16* qkv  = Wmt + 16384;              // 8,388,608
    u16* qlat = qkv + 8388608;            // 4,194,304
    u16* klat = qlat + 4194304;           // 4,194,304
    u16* mlo  = klat + 4194304;           // 8,388,608
    u16* T1   = mlo + 8388608;            // 8,192 (latent weight transposes)
    // aliases (lifetimes checked):
    u16* Vt    = Wqt;   // 8.4M elems over Wqt+Wkt (dead after k-GEMM)
    u16* AO    = xb;    // dead after v-GEMM
    u16* mixed = qkv;   // dead after vtrans

    dim3 gemm_g(16, 32);   // (N/128, M/128)
    dim3 head_g(16, 32);   // (S/128, B*H)

    cvt_bf16<<<2048, 256, 0, stream>>>(x, xb, 1048576);
    wtrans<<<dim3(32, 32), 256, 0, stream>>>(Wq, Wqt, 2048, 2048);
    wtrans<<<dim3(32, 32), 256, 0, stream>>>(Wk, Wkt, 2048, 2048);
    wtrans<<<dim3(32, 32), 256, 0, stream>>>(Wv, Wvt, 2048, 2048);
    wtrans<<<dim3(32, 32), 256, 0, stream>>>(Wo, Wot, 2048, 2048);
    wtrans<<<dim3(2, 2), 256, 0, stream>>>(Wm, Wmt, 128, 128);

    // q
    gemm_bf16<u16, false><<<gemm_g, 256, 0, stream>>>(xb, nullptr, Wqt, bq, qkv, 4096, 2048, 2048);
    wtrans<<<dim3(1, 2), 256, 0, stream>>>(Wql, T1, 128, 64);
    headgemm<0><<<head_g, 256, 0, stream>>>(qkv, T1, bql, qlat, nullptr);
    // k
    gemm_bf16<u16, false><<<gemm_g, 256, 0, stream>>>(xb, nullptr, Wkt, bk, qkv, 4096, 2048, 2048);
    wtrans<<<dim3(1, 2), 256, 0, stream>>>(Wkl, T1, 128, 64);
    headgemm<0><<<head_g, 256, 0, stream>>>(qkv, T1, bkl, klat, nullptr);
    // v
    gemm_bf16<u16, false><<<gemm_g, 256, 0, stream>>>(xb, nullptr, Wvt, bv, qkv, 4096, 2048, 2048);
    vtrans<<<dim3(64, 32), 256, 0, stream>>>(qkv, Vt);
    // attention
    attn_mfma<<<head_g, 256, 0, stream>>>(qlat, klat, Vt, AO);
    // mixer (hi/lo split output)
    headgemm<1><<<head_g, 256, 0, stream>>>(AO, Wmt, bm, mixed, mlo);
    // final projection, split-bf16 A for precision
    gemm_bf16<float, true><<<gemm_g, 256, 0, stream>>>(mixed, mlo, Wot, bo, out, 4096, 2048, 2048);
}

// Round 4
// 370.581 us; speedup vs baseline: 8.1088x; 1.2523x over previous
//
#include <hip/hip_runtime.h>
#include <stdint.h>
#include <math.h>

#define B_ 2
#define S_ 2048
#define E_ 2048
#define H_ 16
#define DH_ 128
#define L_ 64

typedef unsigned short u16;
typedef __attribute__((ext_vector_type(4))) float f32x4;
typedef __attribute__((ext_vector_type(8))) short short8;
typedef __attribute__((ext_vector_type(4))) short short4v;

__device__ __forceinline__ u16 f2bf(float f) {
    union { float f; uint32_t u; } c; c.f = f;
    uint32_t u = c.u + 0x7fff + ((c.u >> 16) & 1);
    return (u16)(u >> 16);
}
__device__ __forceinline__ float bf2f(u16 h) {
    union { uint32_t u; float f; } c; c.u = ((uint32_t)h) << 16;
    return c.f;
}
__device__ __forceinline__ float elu1(float x) {
    return x > 0.f ? x + 1.f : __expf(x);
}
__device__ __forceinline__ float gelu_tanh(float x) {
    float z = 0.7978845608028654f * (x + 0.044715f * x * x * x);
    float az = fabsf(z);
    float e = __expf(-2.f * az);
    float t = (1.f - e) / (1.f + e);
    t = (z >= 0.f) ? t : -t;
    return 0.5f * x * (1.f + t);
}
// async global->LDS, 16B per lane, LDS dest lane-linear (wave-uniform base + lane*16)
__device__ __forceinline__ void async16(u16* lds_dst, const u16* g_src) {
    __builtin_amdgcn_global_load_lds(
        (const __attribute__((address_space(1))) uint32_t*)g_src,
        (__attribute__((address_space(3))) uint32_t*)lds_dst, 16, 0, 0);
}
// element offset within a row for swizzled 8-u16 chunk reads:
// storage has chunk c of row at (c ^ (row&7))*8
__device__ __forceinline__ int swz_off(int row, int chunk) {
    return ((chunk ^ (row & 7)) << 3);
}

// ---------------------------------------------------------------------------
// f32 -> bf16 elementwise, 8/thread
// ---------------------------------------------------------------------------
__global__ __launch_bounds__(256) void cvt_bf16(const float* __restrict__ in,
                                                u16* __restrict__ out, int n8) {
    for (int i = blockIdx.x * 256 + threadIdx.x; i < n8; i += gridDim.x * 256) {
        float4 a = reinterpret_cast<const float4*>(in)[2 * i];
        float4 b = reinterpret_cast<const float4*>(in)[2 * i + 1];
        u16 u[8] __attribute__((aligned(16)));
        u[0] = f2bf(a.x); u[1] = f2bf(a.y); u[2] = f2bf(a.z); u[3] = f2bf(a.w);
        u[4] = f2bf(b.x); u[5] = f2bf(b.y); u[6] = f2bf(b.z); u[7] = f2bf(b.w);
        reinterpret_cast<int4*>(out)[i] = *(const int4*)u;
    }
}

// ---------------------------------------------------------------------------
// W[K][N] f32 -> Wt[N][K] bf16  (64x64 tiles)
// ---------------------------------------------------------------------------
__global__ __launch_bounds__(256) void wtrans(const float* __restrict__ W,
                                              u16* __restrict__ Wt, int K, int N) {
    __shared__ u16 t[64][68];
    const int tid = threadIdx.x;
    const int n0 = blockIdx.x * 64, k0 = blockIdx.y * 64;
    const int c4 = (tid & 15) * 4, r = tid >> 4;
    #pragma unroll
    for (int i = 0; i < 4; i++) {
        int row = r + 16 * i;
        float4 v = *reinterpret_cast<const float4*>(&W[(size_t)(k0 + row) * N + n0 + c4]);
        t[c4 + 0][row] = f2bf(v.x); t[c4 + 1][row] = f2bf(v.y);
        t[c4 + 2][row] = f2bf(v.z); t[c4 + 3][row] = f2bf(v.w);
    }
    __syncthreads();
    #pragma unroll
    for (int i = 0; i < 4; i++) {
        int nr = r + 16 * i;
        ushort4 o = *reinterpret_cast<const ushort4*>(&t[nr][c4]);
        *reinterpret_cast<ushort4*>(&Wt[(size_t)(n0 + nr) * K + k0 + c4]) = o;
    }
}

// ---------------------------------------------------------------------------
// v[b][s][h*128+d] bf16 -> Vt[bh][d][s] bf16 (64x64 tiles)
// grid: ((S/64)*2, B*H)
// ---------------------------------------------------------------------------
__global__ __launch_bounds__(256) void vtrans(const u16* __restrict__ vb,
                                              u16* __restrict__ Vt) {
    __shared__ u16 t[64][66];
    const int bh = blockIdx.y, b = bh >> 4, h = bh & 15;
    const int s0 = (blockIdx.x >> 1) * 64, d0 = (blockIdx.x & 1) * 64;
    const int tid = threadIdx.x;
    const int rr = tid >> 3, c8 = (tid & 7) * 8;
    #pragma unroll
    for (int i = 0; i < 2; i++) {
        int sr = rr + 32 * i;
        int4 v = *reinterpret_cast<const int4*>(
            &vb[((size_t)(b * S_) + s0 + sr) * E_ + h * DH_ + d0 + c8]);
        const u16* pv = (const u16*)&v;
        #pragma unroll
        for (int j = 0; j < 8; j++) t[sr][c8 + j] = pv[j];
    }
    __syncthreads();
    #pragma unroll
    for (int i = 0; i < 2; i++) {
        int dr = rr + 32 * i;
        u16 u[8] __attribute__((aligned(16)));
        #pragma unroll
        for (int j = 0; j < 8; j++) u[j] = t[c8 + j][dr];
        *reinterpret_cast<int4*>(&Vt[((size_t)(bh * 128) + d0 + dr) * S_ + s0 + c8]) =
            *(const int4*)u;
    }
}

// ---------------------------------------------------------------------------
// C[M,N] = A[M,K]bf16 @ Wt[N,K]bf16^T + bias. 128x128 tile, BK=64, 4 waves.
// DUAL: C = (A + A2) @ Wt^T (split-bf16 A for precision).
// grid (N/128, M/128), block 256.
// ---------------------------------------------------------------------------
template <typename OutT, bool DUAL>
__global__ __launch_bounds__(256) void gemm_bf16(
    const u16* __restrict__ A, const u16* __restrict__ A2,
    const u16* __restrict__ Wt, const float* __restrict__ bias,
    OutT* __restrict__ C, int M, int N, int K)
{
    __shared__ u16 lds[DUAL ? 24576 : 16384];
    const int tid = threadIdx.x, l = tid & 63, w = tid >> 6;
    const int wr = w >> 1, wc = w & 1;
    const int row0 = blockIdx.y * 128, col0 = blockIdx.x * 128;

    f32x4 zero = {0.f, 0.f, 0.f, 0.f};
    f32x4 acc[4][4];
    #pragma unroll
    for (int i = 0; i < 4; i++)
        #pragma unroll
        for (int j = 0; j < 4; j++) acc[i][j] = zero;

    for (int k0 = 0; k0 < K; k0 += 64) {
        #pragma unroll
        for (int i = 0; i < 4; i++) {
            int lin = i * 256 + tid, row = lin >> 3, c = lin & 7;
            int sc = swz_off(row, c);
            async16(&lds[lin * 8], &A[(size_t)(row0 + row) * K + k0 + sc]);
            async16(&lds[8192 + lin * 8], &Wt[(size_t)(col0 + row) * K + k0 + sc]);
            if (DUAL) async16(&lds[16384 + lin * 8], &A2[(size_t)(row0 + row) * K + k0 + sc]);
        }
        __syncthreads();
        #pragma unroll
        for (int ks = 0; ks < 2; ks++) {
            short8 af[4], bf[4], af2[4];
            #pragma unroll
            for (int mi = 0; mi < 4; mi++) {
                int row = 64 * wr + 16 * mi + (l & 15);
                int idx = row * 64 + swz_off(row, ks * 4 + (l >> 4));
                af[mi] = *reinterpret_cast<const short8*>(&lds[idx]);
                if (DUAL) af2[mi] = *reinterpret_cast<const short8*>(&lds[16384 + idx]);
            }
            #pragma unroll
            for (int ni = 0; ni < 4; ni++) {
                int row = 64 * wc + 16 * ni + (l & 15);
                int idx = 8192 + row * 64 + swz_off(row, ks * 4 + (l >> 4));
                bf[ni] = *reinterpret_cast<const short8*>(&lds[idx]);
            }
            #pragma unroll
            for (int mi = 0; mi < 4; mi++)
                #pragma unroll
                for (int ni = 0; ni < 4; ni++) {
                    acc[mi][ni] = __builtin_amdgcn_mfma_f32_16x16x32_bf16(
                        af[mi], bf[ni], acc[mi][ni], 0, 0, 0);
                    if (DUAL)
                        acc[mi][ni] = __builtin_amdgcn_mfma_f32_16x16x32_bf16(
                            af2[mi], bf[ni], acc[mi][ni], 0, 0, 0);
                }
        }
        __syncthreads();
    }
    #pragma unroll
    for (int mi = 0; mi < 4; mi++)
        #pragma unroll
        for (int ni = 0; ni < 4; ni++) {
            int col = col0 + 64 * wc + 16 * ni + (l & 15);
            float bv = bias[col];
            #pragma unroll
            for (int j = 0; j < 4; j++) {
                int row = row0 + 64 * wr + 16 * mi + (l >> 4) * 4 + j;
                float v = acc[mi][ni][j] + bv;
                if (sizeof(OutT) == 2)
                    C[(size_t)row * N + col] = (OutT)f2bf(v);
                else
                    C[(size_t)row * N + col] = (OutT)v;
            }
        }
}

// ---------------------------------------------------------------------------
// Per-head small GEMM, K=128 one-shot. MODE 0: latent (NT=64, elu+1, bf16 out
// [bh][s][64]); MODE 1: mixer (NT=128, gelu, dual bf16 hi/lo out [b][s][E]).
// grid (S/128, B*H), block 256.
// ---------------------------------------------------------------------------
template <int MODE>
__global__ __launch_bounds__(256) void headgemm(
    const u16* __restrict__ A, const u16* __restrict__ Wt,
    const float* __restrict__ bias, u16* __restrict__ out, u16* __restrict__ out2)
{
    constexpr int NT = (MODE == 0) ? 64 : 128;
    __shared__ u16 lds[16384 + NT * 128];
    const int tid = threadIdx.x, l = tid & 63, w = tid >> 6;
    const int s0 = blockIdx.x * 128, bh = blockIdx.y, b = bh >> 4, h = bh & 15;

    #pragma unroll
    for (int i = 0; i < 8; i++) {
        int lin = i * 256 + tid, row = lin >> 4, c = lin & 15;
        int sc = swz_off(row, c);
        const u16* src = (MODE == 0)
            ? &A[((size_t)(b * S_ + s0 + row)) * E_ + h * DH_ + sc]
            : &A[((size_t)(bh * S_ + s0 + row)) * DH_ + sc];
        async16(&lds[lin * 8], src);
    }
    #pragma unroll
    for (int i = 0; i < NT * 16 / 256; i++) {
        int lin = i * 256 + tid, n = lin >> 4, c = lin & 15;
        int sc = swz_off(n, c);
        async16(&lds[16384 + lin * 8], &Wt[(size_t)n * 128 + sc]);
    }
    __syncthreads();

    f32x4 zero = {0.f, 0.f, 0.f, 0.f};
    f32x4 acc[2][NT / 16];
    #pragma unroll
    for (int mi = 0; mi < 2; mi++)
        #pragma unroll
        for (int ni = 0; ni < NT / 16; ni++) acc[mi][ni] = zero;

    #pragma unroll
    for (int ks = 0; ks < 4; ks++) {
        short8 af[2];
        #pragma unroll
        for (int mi = 0; mi < 2; mi++) {
            int row = 32 * w + 16 * mi + (l & 15);
            int idx = row * 128 + swz_off(row, ks * 4 + (l >> 4));
            af[mi] = *reinterpret_cast<const short8*>(&lds[idx]);
        }
        #pragma unroll
        for (int ni = 0; ni < NT / 16; ni++) {
            int n = 16 * ni + (l & 15);
            int idx = 16384 + n * 128 + swz_off(n, ks * 4 + (l >> 4));
            short8 bf = *reinterpret_cast<const short8*>(&lds[idx]);
            #pragma unroll
            for (int mi = 0; mi < 2; mi++)
                acc[mi][ni] = __builtin_amdgcn_mfma_f32_16x16x32_bf16(
                    af[mi], bf, acc[mi][ni], 0, 0, 0);
        }
    }

    #pragma unroll
    for (int mi = 0; mi < 2; mi++)
        #pragma unroll
        for (int ni = 0; ni < NT / 16; ni++) {
            int col = 16 * ni + (l & 15);
            float bv = bias[col];
            #pragma unroll
            for (int j = 0; j < 4; j++) {
                int q = s0 + 32 * w + 16 * mi + (l >> 4) * 4 + j;
                float v = acc[mi][ni][j] + bv;
                if (MODE == 0) {
                    v = elu1(v);
                    out[((size_t)bh * S_ + q) * 64 + col] = f2bf(v);
                } else {
                    v = gelu_tanh(v);
                    u16 hi = f2bf(v);
                    float rem = v - bf2f(hi);
                    size_t o = ((size_t)(b * S_ + q)) * E_ + h * DH_ + col;
                    out[o] = hi;
                    out2[o] = f2bf(rem);
                }
            }
        }
}

// ---------------------------------------------------------------------------
// Fused block attention v2: swapped QK^T (S^T in regs), in-register softmax,
// P direct to 16x16x16 MFMA B-fragments (no P LDS), PV -> Ot^T[d][q].
// 64-key chunks, double-buffered K/V staging, one barrier per chunk.
// LDS (u16 elems): Q [0,8192); Kbuf[2] at 8192/12288 ([64][64]);
// Vbuf[2] at 16384/24576 ([128 d][64 f]). Total 64 KB -> 2 blocks/CU.
// grid (S/128, B*H), block 256 (4 waves, wave w owns q in [32w,32w+32)).
// ---------------------------------------------------------------------------
__global__ __launch_bounds__(256, 2) void attn_mfma(
    const u16* __restrict__ qlat, const u16* __restrict__ klat,
    const u16* __restrict__ Vt, u16* __restrict__ AO)
{
    __shared__ u16 pool[32768];
    const int tid = threadIdx.x, l = tid & 63, w = tid >> 6;
    const int g = l >> 4;          // 0..3 lane group
    const int qi = blockIdx.x, bh = blockIdx.y;
    const u16* klat_bh = klat + (size_t)bh * S_ * L_;
    const u16* vt_bh = Vt + (size_t)bh * 128 * S_;
    const int q0 = qi * 128;

    // prologue: stage Q [128][64] + chunk 0 of K/V
    #pragma unroll
    for (int i = 0; i < 4; i++) {
        int lin = i * 256 + tid, row = lin >> 3, c = lin & 7;
        async16(&pool[lin * 8],
                &qlat[((size_t)bh * S_ + q0 + row) * 64 + swz_off(row, c)]);
    }
    #pragma unroll
    for (int i = 0; i < 2; i++) {
        int lin = i * 256 + tid, row = lin >> 3, c = lin & 7;
        async16(&pool[8192 + lin * 8], &klat_bh[(size_t)row * 64 + swz_off(row, c)]);
    }
    #pragma unroll
    for (int i = 0; i < 4; i++) {
        int lin = i * 256 + tid, d = lin >> 3, c = lin & 7;
        async16(&pool[16384 + lin * 8], &vt_bh[(size_t)d * S_ + swz_off(d, c)]);
    }
    __syncthreads();

    // Q fragments (B-operand: col q = l&15 within tile qt)
    short8 qf[2][2];
    #pragma unroll
    for (int qt = 0; qt < 2; qt++)
        #pragma unroll
        for (int ks = 0; ks < 2; ks++) {
            int row = 32 * w + 16 * qt + (l & 15);
            int idx = row * 64 + swz_off(row, ks * 4 + g);
            qf[qt][ks] = *reinterpret_cast<const short8*>(&pool[idx]);
        }

    f32x4 zero = {0.f, 0.f, 0.f, 0.f};
    f32x4 Ot[8][2], Op[8][2];
    float m_reg[2], l_reg[2];
    #pragma unroll
    for (int nd = 0; nd < 8; nd++)
        #pragma unroll
        for (int qt = 0; qt < 2; qt++) { Ot[nd][qt] = zero; Op[nd][qt] = zero; }
    #pragma unroll
    for (int qt = 0; qt < 2; qt++) { m_reg[qt] = -1e30f; l_reg[qt] = 0.f; }

    for (int t = 0; t < 32; t++) {        // 32 chunks of 64 keys
        const int cur = t & 1;
        if (t < 31) {                      // prefetch next chunk
            const int f0 = (t + 1) * 64, nb = cur ^ 1;
            #pragma unroll
            for (int i = 0; i < 2; i++) {
                int lin = i * 256 + tid, row = lin >> 3, c = lin & 7;
                async16(&pool[8192 + nb * 4096 + lin * 8],
                        &klat_bh[(size_t)(f0 + row) * 64 + swz_off(row, c)]);
            }
            #pragma unroll
            for (int i = 0; i < 4; i++) {
                int lin = i * 256 + tid, d = lin >> 3, c = lin & 7;
                async16(&pool[16384 + nb * 8192 + lin * 8],
                        &vt_bh[(size_t)d * S_ + f0 + swz_off(d, c)]);
            }
        }
        const u16* Kb = &pool[8192 + cur * 4096];
        const u16* Vb = &pool[16384 + cur * 8192];

        // S^T = K x Q^T : accS[fi][qt], rows f = 16fi+4g+j, cols q (l&15)
        f32x4 accS[4][2];
        #pragma unroll
        for (int fi = 0; fi < 4; fi++)
            #pragma unroll
            for (int qt = 0; qt < 2; qt++) accS[fi][qt] = zero;
        #pragma unroll
        for (int ks = 0; ks < 2; ks++) {
            short8 kfrag[4];
            #pragma unroll
            for (int fi = 0; fi < 4; fi++) {
                int row = 16 * fi + (l & 15);
                kfrag[fi] = *reinterpret_cast<const short8*>(
                    &Kb[row * 64 + swz_off(row, ks * 4 + g)]);
            }
            #pragma unroll
            for (int fi = 0; fi < 4; fi++)
                #pragma unroll
                for (int qt = 0; qt < 2; qt++)
                    accS[fi][qt] = __builtin_amdgcn_mfma_f32_16x16x32_bf16(
                        kfrag[fi], qf[qt][ks], accS[fi][qt], 0, 0, 0);
        }

        // in-register online softmax over this 64-key chunk
        short4v pf[2][4];
        #pragma unroll
        for (int qt = 0; qt < 2; qt++) {
            float mx = accS[0][qt][0];
            #pragma unroll
            for (int fi = 0; fi < 4; fi++)
                #pragma unroll
                for (int j = 0; j < 4; j++) mx = fmaxf(mx, accS[fi][qt][j]);
            mx *= 0.125f;
            mx = fmaxf(mx, __shfl_xor(mx, 16));
            mx = fmaxf(mx, __shfl_xor(mx, 32));
            float mo = m_reg[qt];
            float mn = fmaxf(mo, mx);
            m_reg[qt] = mn;
            float alpha = __expf(mo - mn);
            float sum = 0.f;
            #pragma unroll
            for (int fi = 0; fi < 4; fi++) {
                float p[4];
                #pragma unroll
                for (int j = 0; j < 4; j++) {
                    p[j] = __expf(accS[fi][qt][j] * 0.125f - mn);
                    sum += p[j];
                }
                short4v pk;
                pk[0] = (short)f2bf(p[0]); pk[1] = (short)f2bf(p[1]);
                pk[2] = (short)f2bf(p[2]); pk[3] = (short)f2bf(p[3]);
                pf[qt][fi] = pk;
            }
            sum += __shfl_xor(sum, 16);
            sum += __shfl_xor(sum, 32);
            l_reg[qt] = l_reg[qt] * alpha + sum;
            if (__any(mx > mo)) {
                #pragma unroll
                for (int nd = 0; nd < 8; nd++) Op[nd][qt] *= alpha;
            }
        }

        // PV: Ot^T[d][q] += Vt[d][f] x P^T[f][q]   (16x16x16, k-tiles kt)
        #pragma unroll
        for (int kt = 0; kt < 4; kt++) {
            int fl = 16 * kt + 4 * g;
            int fch = fl >> 3, fsub = fl & 7;
            #pragma unroll
            for (int nd = 0; nd < 8; nd++) {
                int d = 16 * nd + (l & 15);
                short4v vfrag = *reinterpret_cast<const short4v*>(
                    &Vb[d * 64 + ((fch ^ (d & 7)) << 3) + fsub]);
                #pragma unroll
                for (int qt = 0; qt < 2; qt++)
                    Op[nd][qt] = __builtin_amdgcn_mfma_f32_16x16x16bf16_1k(
                        vfrag, pf[qt][kt], Op[nd][qt], 0, 0, 0);
            }
        }

        if ((t & 7) == 7) {   // kv-block boundary: fold normalized partial
            #pragma unroll
            for (int qt = 0; qt < 2; qt++) {
                float linv = 1.f / l_reg[qt];
                #pragma unroll
                for (int nd = 0; nd < 8; nd++) {
                    Ot[nd][qt] += Op[nd][qt] * linv;
                    Op[nd][qt] = zero;
                }
                m_reg[qt] = -1e30f; l_reg[qt] = 0.f;
            }
        }
        __syncthreads();   // drains prefetch (vmcnt) + this chunk's lds reads
    }

    // epilogue: lane holds Ot^T[d = 16nd+4g+j][q = 32w+16qt+(l&15)]
    #pragma unroll
    for (int nd = 0; nd < 8; nd++)
        #pragma unroll
        for (int qt = 0; qt < 2; qt++) {
            int q = q0 + 32 * w + 16 * qt + (l & 15);
            u16 o[4] __attribute__((aligned(8)));
            #pragma unroll
            for (int j = 0; j < 4; j++) o[j] = f2bf(Ot[nd][qt][j]);
            *reinterpret_cast<ushort4*>(&AO[((size_t)bh * S_ + q) * 128 + 16 * nd + 4 * g]) =
                *(const ushort4*)o;
        }
}

// ---------------------------------------------------------------------------
extern "C" void kernel_launch(void* const* d_in, const int* in_sizes, int n_in,
                              void* d_out, int out_size, void* d_ws, size_t ws_size,
                              hipStream_t stream)
{
    const float* x   = (const float*)d_in[0];
    const float* Wq  = (const float*)d_in[1];
    const float* bq  = (const float*)d_in[2];
    const float* Wk  = (const float*)d_in[3];
    const float* bk  = (const float*)d_in[4];
    const float* Wv  = (const float*)d_in[5];
    const float* bv  = (const float*)d_in[6];
    const float* Wo  = (const float*)d_in[7];
    const float* bo  = (const float*)d_in[8];
    const float* Wql = (const float*)d_in[9];
    const float* bql = (const float*)d_in[10];
    const float* Wkl = (const float*)d_in[11];
    const float* bkl = (const float*)d_in[12];
    const float* Wm  = (const float*)d_in[13];
    const float* bm  = (const float*)d_in[14];
    float* out = (float*)d_out;

    u16* ws0  = (u16*)d_ws;
    u16* xb   = ws0;                      // 8,388,608
    u16* Wqt  = ws0 + 8388608;            // 4,194,304
    u16* Wkt  = Wqt + 4194304;
    u16* Wvt  = Wkt + 4194304;
    u16* Wot  = Wvt + 4194304;
    u16* Wmt  = Wot + 4194304;            // 16,384
    u16* qkv  = Wmt + 16384;              // 8,388,608
    u16* qlat = qkv + 8388608;            // 4,194,304
    u16* klat = qlat + 4194304;           // 4,194,304
    u16* mlo  = klat + 4194304;           // 8,388,608
    u16* T1   = mlo + 8388608;            // 8,192 (latent weight transposes)
    // aliases (lifetimes checked):
    u16* Vt    = Wqt;   // 8.4M elems over Wqt+Wkt (dead after k-GEMM)
    u16* AO    = xb;    // dead after v-GEMM
    u16* mixed = qkv;   // dead after vtrans

    dim3 gemm_g(16, 32);   // (N/128, M/128)
    dim3 head_g(16, 32);   // (S/128, B*H)

    cvt_bf16<<<2048, 256, 0, stream>>>(x, xb, 1048576);
    wtrans<<<dim3(32, 32), 256, 0, stream>>>(Wq, Wqt, 2048, 2048);
    wtrans<<<dim3(32, 32), 256, 0, stream>>>(Wk, Wkt, 2048, 2048);
    wtrans<<<dim3(32, 32), 256, 0, stream>>>(Wv, Wvt, 2048, 2048);
    wtrans<<<dim3(32, 32), 256, 0, stream>>>(Wo, Wot, 2048, 2048);
    wtrans<<<dim3(2, 2), 256, 0, stream>>>(Wm, Wmt, 128, 128);

    // q
    gemm_bf16<u16, false><<<gemm_g, 256, 0, stream>>>(xb, nullptr, Wqt, bq, qkv, 4096, 2048, 2048);
    wtrans<<<dim3(1, 2), 256, 0, stream>>>(Wql, T1, 128, 64);
    headgemm<0><<<head_g, 256, 0, stream>>>(qkv, T1, bql, qlat, nullptr);
    // k
    gemm_bf16<u16, false><<<gemm_g, 256, 0, stream>>>(xb, nullptr, Wkt, bk, qkv, 4096, 2048, 2048);
    wtrans<<<dim3(1, 2), 256, 0, stream>>>(Wkl, T1, 128, 64);
    headgemm<0><<<head_g, 256, 0, stream>>>(qkv, T1, bkl, klat, nullptr);
    // v
    gemm_bf16<u16, false><<<gemm_g, 256, 0, stream>>>(xb, nullptr, Wvt, bv, qkv, 4096, 2048, 2048);
    vtrans<<<dim3(64, 32), 256, 0, stream>>>(qkv, Vt);
    // attention
    attn_mfma<<<head_g, 256, 0, stream>>>(qlat, klat, Vt, AO);
    // mixer (hi/lo split output)
    headgemm<1><<<head_g, 256, 0, stream>>>(AO, Wmt, bm, mixed, mlo);
    // final projection, split-bf16 A for precision
    gemm_bf16<float, true><<<gemm_g, 256, 0, stream>>>(mixed, mlo, Wot, bo, out, 4096, 2048, 2048);
}

// Round 6
// 327.109 us; speedup vs baseline: 9.1865x; 1.1329x over previous
//
#include <hip/hip_runtime.h>
#include <stdint.h>
#include <math.h>

#define B_ 2
#define S_ 2048
#define E_ 2048
#define H_ 16
#define DH_ 128
#define L_ 64

typedef unsigned short u16;
typedef __attribute__((ext_vector_type(4))) float f32x4;
typedef __attribute__((ext_vector_type(8))) short short8;
typedef __attribute__((ext_vector_type(4))) short short4v;

__device__ __forceinline__ u16 f2bf(float f) {
    union { float f; uint32_t u; } c; c.f = f;
    uint32_t u = c.u + 0x7fff + ((c.u >> 16) & 1);
    return (u16)(u >> 16);
}
__device__ __forceinline__ float bf2f(u16 h) {
    union { uint32_t u; float f; } c; c.u = ((uint32_t)h) << 16;
    return c.f;
}
__device__ __forceinline__ float elu1(float x) {
    return x > 0.f ? x + 1.f : __expf(x);
}
__device__ __forceinline__ float gelu_tanh(float x) {
    float z = 0.7978845608028654f * (x + 0.044715f * x * x * x);
    float az = fabsf(z);
    float e = __expf(-2.f * az);
    float t = (1.f - e) / (1.f + e);
    t = (z >= 0.f) ? t : -t;
    return 0.5f * x * (1.f + t);
}
// async global->LDS, 16B per lane, LDS dest lane-linear (wave-uniform base + lane*16)
__device__ __forceinline__ void async16(u16* lds_dst, const u16* g_src) {
    __builtin_amdgcn_global_load_lds(
        (const __attribute__((address_space(1))) uint32_t*)g_src,
        (__attribute__((address_space(3))) uint32_t*)lds_dst, 16, 0, 0);
}
// element offset within a row for swizzled 8-u16 chunk reads:
// storage has chunk c of row at (c ^ (row&7))*8
__device__ __forceinline__ int swz_off(int row, int chunk) {
    return ((chunk ^ (row & 7)) << 3);
}

// ---------------------------------------------------------------------------
// f32 -> bf16 elementwise, 8/thread
// ---------------------------------------------------------------------------
__global__ __launch_bounds__(256) void cvt_bf16(const float* __restrict__ in,
                                                u16* __restrict__ out, int n8) {
    for (int i = blockIdx.x * 256 + threadIdx.x; i < n8; i += gridDim.x * 256) {
        float4 a = reinterpret_cast<const float4*>(in)[2 * i];
        float4 b = reinterpret_cast<const float4*>(in)[2 * i + 1];
        u16 u[8] __attribute__((aligned(16)));
        u[0] = f2bf(a.x); u[1] = f2bf(a.y); u[2] = f2bf(a.z); u[3] = f2bf(a.w);
        u[4] = f2bf(b.x); u[5] = f2bf(b.y); u[6] = f2bf(b.z); u[7] = f2bf(b.w);
        reinterpret_cast<int4*>(out)[i] = *(const int4*)u;
    }
}

// ---------------------------------------------------------------------------
// W[K][N] f32 -> Wt[N][K] bf16  (64x64 tiles)
// ---------------------------------------------------------------------------
__global__ __launch_bounds__(256) void wtrans(const float* __restrict__ W,
                                              u16* __restrict__ Wt, int K, int N) {
    __shared__ u16 t[64][68];
    const int tid = threadIdx.x;
    const int n0 = blockIdx.x * 64, k0 = blockIdx.y * 64;
    const int c4 = (tid & 15) * 4, r = tid >> 4;
    #pragma unroll
    for (int i = 0; i < 4; i++) {
        int row = r + 16 * i;
        float4 v = *reinterpret_cast<const float4*>(&W[(size_t)(k0 + row) * N + n0 + c4]);
        t[c4 + 0][row] = f2bf(v.x); t[c4 + 1][row] = f2bf(v.y);
        t[c4 + 2][row] = f2bf(v.z); t[c4 + 3][row] = f2bf(v.w);
    }
    __syncthreads();
    #pragma unroll
    for (int i = 0; i < 4; i++) {
        int nr = r + 16 * i;
        ushort4 o = *reinterpret_cast<const ushort4*>(&t[nr][c4]);
        *reinterpret_cast<ushort4*>(&Wt[(size_t)(n0 + nr) * K + k0 + c4]) = o;
    }
}

// ---------------------------------------------------------------------------
// v[b][s][h*128+d] bf16 -> Vt[bh][d][s] bf16 (64x64 tiles)
// grid: ((S/64)*2, B*H)
// ---------------------------------------------------------------------------
__global__ __launch_bounds__(256) void vtrans(const u16* __restrict__ vb,
                                              u16* __restrict__ Vt) {
    __shared__ u16 t[64][66];
    const int bh = blockIdx.y, b = bh >> 4, h = bh & 15;
    const int s0 = (blockIdx.x >> 1) * 64, d0 = (blockIdx.x & 1) * 64;
    const int tid = threadIdx.x;
    const int rr = tid >> 3, c8 = (tid & 7) * 8;
    #pragma unroll
    for (int i = 0; i < 2; i++) {
        int sr = rr + 32 * i;
        int4 v = *reinterpret_cast<const int4*>(
            &vb[((size_t)(b * S_) + s0 + sr) * E_ + h * DH_ + d0 + c8]);
        const u16* pv = (const u16*)&v;
        #pragma unroll
        for (int j = 0; j < 8; j++) t[sr][c8 + j] = pv[j];
    }
    __syncthreads();
    #pragma unroll
    for (int i = 0; i < 2; i++) {
        int dr = rr + 32 * i;
        u16 u[8] __attribute__((aligned(16)));
        #pragma unroll
        for (int j = 0; j < 8; j++) u[j] = t[c8 + j][dr];
        *reinterpret_cast<int4*>(&Vt[((size_t)(bh * 128) + d0 + dr) * S_ + s0 + c8]) =
            *(const int4*)u;
    }
}

// ---------------------------------------------------------------------------
// beff[outoff + h*64 + n] = sum_d b[h*128+d]*Wl[d][n] + bl[n]   (f32)
// grid 4, block 256
// ---------------------------------------------------------------------------
__global__ __launch_bounds__(256) void beff_kernel(
    const float* __restrict__ b, const float* __restrict__ Wl,
    const float* __restrict__ bl, float* __restrict__ beff, int outoff)
{
    int t = blockIdx.x * 256 + threadIdx.x;
    if (t >= 1024) return;
    int h = t >> 6, n = t & 63;
    float s = bl[n];
    for (int d = 0; d < 128; d++) s += b[h * 128 + d] * Wl[d * 64 + n];
    beff[outoff + t] = s;
}

// ---------------------------------------------------------------------------
// Weff fold: Wefft[outoff + h*64 + nl][k] = sum_d Wlt[nl][d] * W[k][h*128+d]
// W is f32 (reg-staged + converted); Wlt bf16 [64][128]. grid (16 ktiles, 16 heads).
// ---------------------------------------------------------------------------
__global__ __launch_bounds__(256) void weff_kernel(
    const float* __restrict__ W, const u16* __restrict__ Wlt,
    u16* __restrict__ Wefft, int outoff)
{
    __shared__ u16 lds[8192 + 16384];   // A: [64][128], B: [128][128]
    const int tid = threadIdx.x, l = tid & 63, w = tid >> 6;
    const int k0 = blockIdx.x * 128, h = blockIdx.y;

    #pragma unroll
    for (int i = 0; i < 4; i++) {        // stage Wlt [64][128]: 1024 chunks
        int lin = i * 256 + tid, row = lin >> 4, c = lin & 15;
        async16(&lds[lin * 8], &Wlt[row * 128 + swz_off(row, c)]);
    }
    #pragma unroll
    for (int i = 0; i < 16; i++) {       // stage W rows k0..k0+127 (f32 -> bf16)
        int e = (i * 256 + tid) * 4;
        int row = e >> 7, ec = e & 127;
        float4 v4 = *reinterpret_cast<const float4*>(
            &W[(size_t)(k0 + row) * E_ + h * DH_ + ec]);
        u16 u[4] __attribute__((aligned(8)));
        u[0] = f2bf(v4.x); u[1] = f2bf(v4.y); u[2] = f2bf(v4.z); u[3] = f2bf(v4.w);
        int chunk = ec >> 3, half = (ec >> 2) & 1;
        *reinterpret_cast<uint64_t*>(
            &lds[8192 + row * 128 + swz_off(row, chunk) + half * 4]) = *(const uint64_t*)u;
    }
    __syncthreads();

    f32x4 zero = {0.f, 0.f, 0.f, 0.f};
    f32x4 acc[8];
    #pragma unroll
    for (int nt = 0; nt < 8; nt++) acc[nt] = zero;
    #pragma unroll
    for (int ks = 0; ks < 4; ks++) {
        int arow = 16 * w + (l & 15);
        short8 af = *reinterpret_cast<const short8*>(
            &lds[arow * 128 + swz_off(arow, ks * 4 + (l >> 4))]);
        #pragma unroll
        for (int nt = 0; nt < 8; nt++) {
            int brow = 16 * nt + (l & 15);
            short8 bf = *reinterpret_cast<const short8*>(
                &lds[8192 + brow * 128 + swz_off(brow, ks * 4 + (l >> 4))]);
            acc[nt] = __builtin_amdgcn_mfma_f32_16x16x32_bf16(af, bf, acc[nt], 0, 0, 0);
        }
    }
    #pragma unroll
    for (int nt = 0; nt < 8; nt++) {
        int kc = k0 + 16 * nt + (l & 15);
        #pragma unroll
        for (int j = 0; j < 4; j++) {
            int nl = 16 * w + (l >> 4) * 4 + j;
            Wefft[(size_t)(outoff + h * 64 + nl) * E_ + kc] = f2bf(acc[nt][j]);
        }
    }
}

// ---------------------------------------------------------------------------
// C[M,N] = A[M,K]bf16 @ Wt[N,K]bf16^T + bias. 128x128 tile, BK=64, 4 waves.
// DUAL: (A+A2)@Wt^T. EPI: 0 = plain store; 1 = elu1 -> qlat/klat scatter.
// grid (N/128, M/128), block 256.
// ---------------------------------------------------------------------------
template <typename OutT, bool DUAL, int EPI>
__global__ __launch_bounds__(256) void gemm_bf16(
    const u16* __restrict__ A, const u16* __restrict__ A2,
    const u16* __restrict__ Wt, const float* __restrict__ bias,
    OutT* __restrict__ C, u16* __restrict__ latq, u16* __restrict__ latk,
    int M, int N, int K)
{
    __shared__ u16 lds[DUAL ? 24576 : 16384];
    const int tid = threadIdx.x, l = tid & 63, w = tid >> 6;
    const int wr = w >> 1, wc = w & 1;
    const int row0 = blockIdx.y * 128, col0 = blockIdx.x * 128;

    f32x4 zero = {0.f, 0.f, 0.f, 0.f};
    f32x4 acc[4][4];
    #pragma unroll
    for (int i = 0; i < 4; i++)
        #pragma unroll
        for (int j = 0; j < 4; j++) acc[i][j] = zero;

    for (int k0 = 0; k0 < K; k0 += 64) {
        #pragma unroll
        for (int i = 0; i < 4; i++) {
            int lin = i * 256 + tid, row = lin >> 3, c = lin & 7;
            int sc = swz_off(row, c);
            async16(&lds[lin * 8], &A[(size_t)(row0 + row) * K + k0 + sc]);
            async16(&lds[8192 + lin * 8], &Wt[(size_t)(col0 + row) * K + k0 + sc]);
            if (DUAL) async16(&lds[16384 + lin * 8], &A2[(size_t)(row0 + row) * K + k0 + sc]);
        }
        __syncthreads();
        #pragma unroll
        for (int ks = 0; ks < 2; ks++) {
            short8 af[4], bf[4], af2[4];
            #pragma unroll
            for (int mi = 0; mi < 4; mi++) {
                int row = 64 * wr + 16 * mi + (l & 15);
                int idx = row * 64 + swz_off(row, ks * 4 + (l >> 4));
                af[mi] = *reinterpret_cast<const short8*>(&lds[idx]);
                if (DUAL) af2[mi] = *reinterpret_cast<const short8*>(&lds[16384 + idx]);
            }
            #pragma unroll
            for (int ni = 0; ni < 4; ni++) {
                int row = 64 * wc + 16 * ni + (l & 15);
                int idx = 8192 + row * 64 + swz_off(row, ks * 4 + (l >> 4));
                bf[ni] = *reinterpret_cast<const short8*>(&lds[idx]);
            }
            #pragma unroll
            for (int mi = 0; mi < 4; mi++)
                #pragma unroll
                for (int ni = 0; ni < 4; ni++) {
                    acc[mi][ni] = __builtin_amdgcn_mfma_f32_16x16x32_bf16(
                        af[mi], bf[ni], acc[mi][ni], 0, 0, 0);
                    if (DUAL)
                        acc[mi][ni] = __builtin_amdgcn_mfma_f32_16x16x32_bf16(
                            af2[mi], bf[ni], acc[mi][ni], 0, 0, 0);
                }
        }
        __syncthreads();
    }
    #pragma unroll
    for (int mi = 0; mi < 4; mi++)
        #pragma unroll
        for (int ni = 0; ni < 4; ni++) {
            int col = col0 + 64 * wc + 16 * ni + (l & 15);
            float bv = bias[col];
            #pragma unroll
            for (int j = 0; j < 4; j++) {
                int row = row0 + 64 * wr + 16 * mi + (l >> 4) * 4 + j;
                float v = acc[mi][ni][j] + bv;
                if (EPI == 1) {
                    v = elu1(v);
                    u16* dst = (col < 1024) ? latq : latk;
                    int h = (col >> 6) & 15, n = col & 63;
                    int bb = row >> 11, s = row & 2047;
                    dst[(((size_t)bb * 16 + h) * S_ + s) * 64 + n] = f2bf(v);
                } else if (sizeof(OutT) == 2) {
                    C[(size_t)row * N + col] = (OutT)f2bf(v);
                } else {
                    C[(size_t)row * N + col] = (OutT)v;
                }
            }
        }
}

// ---------------------------------------------------------------------------
// Mixer small GEMM, K=128 one-shot: gelu, dual bf16 hi/lo out [b][s][E].
// grid (S/128, B*H), block 256.
// ---------------------------------------------------------------------------
__global__ __launch_bounds__(256) void mixer_gemm(
    const u16* __restrict__ A, const u16* __restrict__ Wt,
    const float* __restrict__ bias, u16* __restrict__ out, u16* __restrict__ out2)
{
    __shared__ u16 lds[16384 + 16384];
    const int tid = threadIdx.x, l = tid & 63, w = tid >> 6;
    const int s0 = blockIdx.x * 128, bh = blockIdx.y, b = bh >> 4, h = bh & 15;

    #pragma unroll
    for (int i = 0; i < 8; i++) {
        int lin = i * 256 + tid, row = lin >> 4, c = lin & 15;
        async16(&lds[lin * 8], &A[((size_t)(bh * S_ + s0 + row)) * DH_ + swz_off(row, c)]);
    }
    #pragma unroll
    for (int i = 0; i < 8; i++) {
        int lin = i * 256 + tid, n = lin >> 4, c = lin & 15;
        async16(&lds[16384 + lin * 8], &Wt[(size_t)n * 128 + swz_off(n, c)]);
    }
    __syncthreads();

    f32x4 zero = {0.f, 0.f, 0.f, 0.f};
    f32x4 acc[2][8];
    #pragma unroll
    for (int mi = 0; mi < 2; mi++)
        #pragma unroll
        for (int ni = 0; ni < 8; ni++) acc[mi][ni] = zero;

    #pragma unroll
    for (int ks = 0; ks < 4; ks++) {
        short8 af[2];
        #pragma unroll
        for (int mi = 0; mi < 2; mi++) {
            int row = 32 * w + 16 * mi + (l & 15);
            af[mi] = *reinterpret_cast<const short8*>(
                &lds[row * 128 + swz_off(row, ks * 4 + (l >> 4))]);
        }
        #pragma unroll
        for (int ni = 0; ni < 8; ni++) {
            int n = 16 * ni + (l & 15);
            short8 bf = *reinterpret_cast<const short8*>(
                &lds[16384 + n * 128 + swz_off(n, ks * 4 + (l >> 4))]);
            #pragma unroll
            for (int mi = 0; mi < 2; mi++)
                acc[mi][ni] = __builtin_amdgcn_mfma_f32_16x16x32_bf16(
                    af[mi], bf, acc[mi][ni], 0, 0, 0);
        }
    }

    #pragma unroll
    for (int mi = 0; mi < 2; mi++)
        #pragma unroll
        for (int ni = 0; ni < 8; ni++) {
            int col = 16 * ni + (l & 15);
            float bv = bias[col];
            #pragma unroll
            for (int j = 0; j < 4; j++) {
                int q = s0 + 32 * w + 16 * mi + (l >> 4) * 4 + j;
                float v = gelu_tanh(acc[mi][ni][j] + bv);
                u16 hi = f2bf(v);
                float rem = v - bf2f(hi);
                size_t o = ((size_t)(b * S_ + q)) * E_ + h * DH_ + col;
                out[o] = hi;
                out2[o] = f2bf(rem);
            }
        }
}

// ---------------------------------------------------------------------------
// Fused block attention (as round 4, unchanged): swapped QK^T, in-register
// softmax, P direct to 16x16x16 MFMA B-frags, PV -> Ot^T[d][q].
// ---------------------------------------------------------------------------
__global__ __launch_bounds__(256, 2) void attn_mfma(
    const u16* __restrict__ qlat, const u16* __restrict__ klat,
    const u16* __restrict__ Vt, u16* __restrict__ AO)
{
    __shared__ u16 pool[32768];
    const int tid = threadIdx.x, l = tid & 63, w = tid >> 6;
    const int g = l >> 4;
    const int qi = blockIdx.x, bh = blockIdx.y;
    const u16* klat_bh = klat + (size_t)bh * S_ * L_;
    const u16* vt_bh = Vt + (size_t)bh * 128 * S_;
    const int q0 = qi * 128;

    #pragma unroll
    for (int i = 0; i < 4; i++) {
        int lin = i * 256 + tid, row = lin >> 3, c = lin & 7;
        async16(&pool[lin * 8],
                &qlat[((size_t)bh * S_ + q0 + row) * 64 + swz_off(row, c)]);
    }
    #pragma unroll
    for (int i = 0; i < 2; i++) {
        int lin = i * 256 + tid, row = lin >> 3, c = lin & 7;
        async16(&pool[8192 + lin * 8], &klat_bh[(size_t)row * 64 + swz_off(row, c)]);
    }
    #pragma unroll
    for (int i = 0; i < 4; i++) {
        int lin = i * 256 + tid, d = lin >> 3, c = lin & 7;
        async16(&pool[16384 + lin * 8], &vt_bh[(size_t)d * S_ + swz_off(d, c)]);
    }
    __syncthreads();

    short8 qf[2][2];
    #pragma unroll
    for (int qt = 0; qt < 2; qt++)
        #pragma unroll
        for (int ks = 0; ks < 2; ks++) {
            int row = 32 * w + 16 * qt + (l & 15);
            qf[qt][ks] = *reinterpret_cast<const short8*>(
                &pool[row * 64 + swz_off(row, ks * 4 + g)]);
        }

    f32x4 zero = {0.f, 0.f, 0.f, 0.f};
    f32x4 Ot[8][2], Op[8][2];
    float m_reg[2], l_reg[2];
    #pragma unroll
    for (int nd = 0; nd < 8; nd++)
        #pragma unroll
        for (int qt = 0; qt < 2; qt++) { Ot[nd][qt] = zero; Op[nd][qt] = zero; }
    #pragma unroll
    for (int qt = 0; qt < 2; qt++) { m_reg[qt] = -1e30f; l_reg[qt] = 0.f; }

    for (int t = 0; t < 32; t++) {
        const int cur = t & 1;
        if (t < 31) {
            const int f0 = (t + 1) * 64, nb = cur ^ 1;
            #pragma unroll
            for (int i = 0; i < 2; i++) {
                int lin = i * 256 + tid, row = lin >> 3, c = lin & 7;
                async16(&pool[8192 + nb * 4096 + lin * 8],
                        &klat_bh[(size_t)(f0 + row) * 64 + swz_off(row, c)]);
            }
            #pragma unroll
            for (int i = 0; i < 4; i++) {
                int lin = i * 256 + tid, d = lin >> 3, c = lin & 7;
                async16(&pool[16384 + nb * 8192 + lin * 8],
                        &vt_bh[(size_t)d * S_ + f0 + swz_off(d, c)]);
            }
        }
        const u16* Kb = &pool[8192 + cur * 4096];
        const u16* Vb = &pool[16384 + cur * 8192];

        f32x4 accS[4][2];
        #pragma unroll
        for (int fi = 0; fi < 4; fi++)
            #pragma unroll
            for (int qt = 0; qt < 2; qt++) accS[fi][qt] = zero;
        #pragma unroll
        for (int ks = 0; ks < 2; ks++) {
            short8 kfrag[4];
            #pragma unroll
            for (int fi = 0; fi < 4; fi++) {
                int row = 16 * fi + (l & 15);
                kfrag[fi] = *reinterpret_cast<const short8*>(
                    &Kb[row * 64 + swz_off(row, ks * 4 + g)]);
            }
            #pragma unroll
            for (int fi = 0; fi < 4; fi++)
                #pragma unroll
                for (int qt = 0; qt < 2; qt++)
                    accS[fi][qt] = __builtin_amdgcn_mfma_f32_16x16x32_bf16(
                        kfrag[fi], qf[qt][ks], accS[fi][qt], 0, 0, 0);
        }

        short4v pf[2][4];
        #pragma unroll
        for (int qt = 0; qt < 2; qt++) {
            float mx = accS[0][qt][0];
            #pragma unroll
            for (int fi = 0; fi < 4; fi++)
                #pragma unroll
                for (int j = 0; j < 4; j++) mx = fmaxf(mx, accS[fi][qt][j]);
            mx *= 0.125f;
            mx = fmaxf(mx, __shfl_xor(mx, 16));
            mx = fmaxf(mx, __shfl_xor(mx, 32));
            float mo = m_reg[qt];
            float mn = fmaxf(mo, mx);
            m_reg[qt] = mn;
            float alpha = __expf(mo - mn);
            float sum = 0.f;
            #pragma unroll
            for (int fi = 0; fi < 4; fi++) {
                float p[4];
                #pragma unroll
                for (int j = 0; j < 4; j++) {
                    p[j] = __expf(accS[fi][qt][j] * 0.125f - mn);
                    sum += p[j];
                }
                short4v pk;
                pk[0] = (short)f2bf(p[0]); pk[1] = (short)f2bf(p[1]);
                pk[2] = (short)f2bf(p[2]); pk[3] = (short)f2bf(p[3]);
                pf[qt][fi] = pk;
            }
            sum += __shfl_xor(sum, 16);
            sum += __shfl_xor(sum, 32);
            l_reg[qt] = l_reg[qt] * alpha + sum;
            if (__any(mx > mo)) {
                #pragma unroll
                for (int nd = 0; nd < 8; nd++) Op[nd][qt] *= alpha;
            }
        }

        #pragma unroll
        for (int kt = 0; kt < 4; kt++) {
            int fl = 16 * kt + 4 * g;
            int fch = fl >> 3, fsub = fl & 7;
            #pragma unroll
            for (int nd = 0; nd < 8; nd++) {
                int d = 16 * nd + (l & 15);
                short4v vfrag = *reinterpret_cast<const short4v*>(
                    &Vb[d * 64 + ((fch ^ (d & 7)) << 3) + fsub]);
                #pragma unroll
                for (int qt = 0; qt < 2; qt++)
                    Op[nd][qt] = __builtin_amdgcn_mfma_f32_16x16x16bf16_1k(
                        vfrag, pf[qt][kt], Op[nd][qt], 0, 0, 0);
            }
        }

        if ((t & 7) == 7) {
            #pragma unroll
            for (int qt = 0; qt < 2; qt++) {
                float linv = 1.f / l_reg[qt];
                #pragma unroll
                for (int nd = 0; nd < 8; nd++) {
                    Ot[nd][qt] += Op[nd][qt] * linv;
                    Op[nd][qt] = zero;
                }
                m_reg[qt] = -1e30f; l_reg[qt] = 0.f;
            }
        }
        __syncthreads();
    }

    #pragma unroll
    for (int nd = 0; nd < 8; nd++)
        #pragma unroll
        for (int qt = 0; qt < 2; qt++) {
            int q = q0 + 32 * w + 16 * qt + (l & 15);
            u16 o[4] __attribute__((aligned(8)));
            #pragma unroll
            for (int j = 0; j < 4; j++) o[j] = f2bf(Ot[nd][qt][j]);
            *reinterpret_cast<ushort4*>(&AO[((size_t)bh * S_ + q) * 128 + 16 * nd + 4 * g]) =
                *(const ushort4*)o;
        }
}

// ---------------------------------------------------------------------------
extern "C" void kernel_launch(void* const* d_in, const int* in_sizes, int n_in,
                              void* d_out, int out_size, void* d_ws, size_t ws_size,
                              hipStream_t stream)
{
    const float* x   = (const float*)d_in[0];
    const float* Wq  = (const float*)d_in[1];
    const float* bq  = (const float*)d_in[2];
    const float* Wk  = (const float*)d_in[3];
    const float* bk  = (const float*)d_in[4];
    const float* Wv  = (const float*)d_in[5];
    const float* bv  = (const float*)d_in[6];
    const float* Wo  = (const float*)d_in[7];
    const float* bo  = (const float*)d_in[8];
    const float* Wql = (const float*)d_in[9];
    const float* bql = (const float*)d_in[10];
    const float* Wkl = (const float*)d_in[11];
    const float* bkl = (const float*)d_in[12];
    const float* Wm  = (const float*)d_in[13];
    const float* bm  = (const float*)d_in[14];
    float* out = (float*)d_out;

    u16* ws0   = (u16*)d_ws;
    u16* xb    = ws0;                     //  8,388,608
    u16* Wefft = ws0 + 8388608;           //  4,194,304 (2048 rows x 2048 k)
    u16* Wvt   = Wefft + 4194304;         //  4,194,304
    u16* Wot   = Wvt + 4194304;           //  4,194,304
    u16* Wmt   = Wot + 4194304;           //  16,384
    u16* Wqlt  = Wmt + 16384;             //  8,192
    u16* Wklt  = Wqlt + 8192;             //  8,192
    float* beff = (float*)(Wklt + 8192);  //  2,048 f32 (4096 u16)
    u16* qkv   = Wklt + 8192 + 4096;      //  8,388,608 (v; then mixed)
    u16* qlat  = qkv + 8388608;           //  4,194,304
    u16* klat  = qlat + 4194304;          //  4,194,304
    u16* mlo   = klat + 4194304;          //  8,388,608
    // aliases (lifetimes checked):
    u16* Vt    = Wefft;  // 8.4M over Wefft+Wvt (both dead before vtrans)
    u16* AO    = xb;     // xb dead after v-GEMM
    u16* mixed = qkv;    // v dead after vtrans

    dim3 gemm_g(16, 32);
    dim3 head_g(16, 32);

    cvt_bf16<<<2048, 256, 0, stream>>>(x, xb, 1048576);
    wtrans<<<dim3(32, 32), 256, 0, stream>>>(Wv, Wvt, 2048, 2048);
    wtrans<<<dim3(32, 32), 256, 0, stream>>>(Wo, Wot, 2048, 2048);
    wtrans<<<dim3(2, 2), 256, 0, stream>>>(Wm, Wmt, 128, 128);
    wtrans<<<dim3(1, 2), 256, 0, stream>>>(Wql, Wqlt, 128, 64);
    wtrans<<<dim3(1, 2), 256, 0, stream>>>(Wkl, Wklt, 128, 64);
    beff_kernel<<<4, 256, 0, stream>>>(bq, Wql, bql, beff, 0);
    beff_kernel<<<4, 256, 0, stream>>>(bk, Wkl, bkl, beff, 1024);
    weff_kernel<<<dim3(16, 16), 256, 0, stream>>>(Wq, Wqlt, Wefft, 0);
    weff_kernel<<<dim3(16, 16), 256, 0, stream>>>(Wk, Wklt, Wefft, 1024);

    // fused q-lat + k-lat projection: elu(x @ Wefft^T + beff)
    gemm_bf16<u16, false, 1><<<gemm_g, 256, 0, stream>>>(
        xb, nullptr, Wefft, beff, (u16*)nullptr, qlat, klat, 4096, 2048, 2048);
    // v
    gemm_bf16<u16, false, 0><<<gemm_g, 256, 0, stream>>>(
        xb, nullptr, Wvt, bv, qkv, nullptr, nullptr, 4096, 2048, 2048);
    vtrans<<<dim3(64, 32), 256, 0, stream>>>(qkv, Vt);
    // attention
    attn_mfma<<<head_g, 256, 0, stream>>>(qlat, klat, Vt, AO);
    // mixer (hi/lo split output)
    mixer_gemm<<<head_g, 256, 0, stream>>>(AO, Wmt, bm, mixed, mlo);
    // final projection, split-bf16 A for precision
    gemm_bf16<float, true, 0><<<gemm_g, 256, 0, stream>>>(
        mixed, mlo, Wot, bo, out, nullptr, nullptr, 4096, 2048, 2048);
}